// Round 7
// baseline (286.251 us; speedup 1.0000x reference)
//
#include <hip/hip_runtime.h>
#include <stdint.h>

#define N_NODES 50000
#define D 128
#define N_EDGES 800000
#define NBUCK 196          // ceil(50000/256) dst buckets (dst>>8)
#define BCAP 8192          // per-bucket capacity (mean 4082)
#define EPB 4096           // edges per block in bucket pass

typedef __attribute__((ext_vector_type(8))) short bf16x8;
typedef __attribute__((ext_vector_type(4))) float f32x4;

// ---------------- bf16 helpers (RNE) ----------------
__device__ __forceinline__ unsigned short f2bf(float f){
  unsigned u = __float_as_uint(f);
  u = u + 0x7FFFu + ((u >> 16) & 1u);
  return (unsigned short)(u >> 16);
}
__device__ __forceinline__ void acc2(float& a, float& b, unsigned w){
  a += __uint_as_float(w << 16);
  b += __uint_as_float(w & 0xFFFF0000u);
}

// ---------------- threefry2x32-20, key=(0,42), partitionable ----------------
__device__ __forceinline__ unsigned rotl32(unsigned x, int r){
  return (x << r) | (x >> (32 - r));
}
__device__ __forceinline__ float dropout_factor(unsigned idx){
  unsigned x0 = 0u, x1 = idx;
  const unsigned ks0 = 0u;
  const unsigned ks1 = 42u;
  const unsigned ks2 = 0x1BD11BDAu ^ 0u ^ 42u;
  x0 += ks0; x1 += ks1;
  #define TFR(r) { x0 += x1; x1 = rotl32(x1,(r)); x1 ^= x0; }
  TFR(13) TFR(15) TFR(26) TFR(6)   x0 += ks1; x1 += ks2 + 1u;
  TFR(17) TFR(29) TFR(16) TFR(24)  x0 += ks2; x1 += ks0 + 2u;
  TFR(13) TFR(15) TFR(26) TFR(6)   x0 += ks0; x1 += ks1 + 3u;
  TFR(17) TFR(29) TFR(16) TFR(24)  x0 += ks1; x1 += ks2 + 4u;
  TFR(13) TFR(15) TFR(26) TFR(6)   x0 += ks2; x1 += ks0 + 5u;
  #undef TFR
  unsigned bits = x0 ^ x1;
  float u = __uint_as_float(0x3F800000u | (bits >> 9)) - 1.0f;
  return (u < 0.8f) ? 1.25f : 0.0f;
}

// ---------------- fused prep + bucket ----------------
// blocks: [0,6250) convert x->Xbf | [6250,6378) packw1 | [6378,6506) packw2
//         [6506,6702) bucket pass (per-block dtype detect)
__global__ __launch_bounds__(256) void prep_bucket_kernel(
    const float* __restrict__ x,
    const float* __restrict__ W1l, const float* __restrict__ W1r,
    const float* __restrict__ W2l, const float* __restrict__ W2r,
    unsigned short* __restrict__ Xbf,
    unsigned short* __restrict__ Wcat1, unsigned short* __restrict__ Wcat2,
    const void* __restrict__ ei, int* __restrict__ gcursor, int* __restrict__ buck)
{
  int b = blockIdx.x, t = threadIdx.x;
  if (b < 6250){
    int i = b * 256 + t;                 // < 1,600,000 exactly
    int r = i >> 5, c4 = (i & 31) * 4;
    float4 v = *(const float4*)(x + (size_t)r * 128 + c4);
    ushort4 o = make_ushort4(f2bf(v.x), f2bf(v.y), f2bf(v.z), f2bf(v.w));
    *(ushort4*)(Xbf + (size_t)r * 128 + c4) = o;
    return;
  }
  if (b < 6506){
    int c = (b < 6378) ? (b - 6250) : (b - 6378);
    const float* Wl = (b < 6378) ? W1l : W2l;
    const float* Wr = (b < 6378) ? W1r : W2r;
    unsigned short* Wc = (b < 6378) ? Wcat1 : Wcat2;
    float v = (t < 128) ? Wl[c * 128 + t] : Wr[c * 128 + (t - 128)];
    Wc[c * 256 + t] = f2bf(v);
    return;
  }
  // ---- bucket pass ----
  __shared__ int hist[NBUCK];
  __shared__ int baseoff[NBUCK];
  __shared__ int nz;
  const int bb = b - 6506;
  const int base = bb * EPB;
  if (t == 0) nz = 0;
  for (int i = t; i < NBUCK; i += 256) hist[i] = 0;
  __syncthreads();
  {  // local dtype detect: int64 edges < 2^32 => all high words zero
    const int* p = (const int*)ei;
    int local = 0;
    for (int i = t; i < 1024; i += 256)
      if (p[2 * i + 1] != 0) local = 1;
    if (local) atomicAdd(&nz, 1);
  }
  __syncthreads();
  const int is64 = (nz == 0);

  int pk[16], bk[16], rk[16];
  #pragma unroll
  for (int j = 0; j < 16; ++j) bk[j] = -1;

  if (is64){
    const long long* p = (const long long*)ei;
    #pragma unroll
    for (int k = 0; k < 8; ++k){
      int e = base + (k * 256 + t) * 2;
      if (e < N_EDGES){
        int4 vs = *(const int4*)(p + e);
        int4 vd = *(const int4*)(p + N_EDGES + e);
        int j0 = k * 2, j1 = k * 2 + 1;
        bk[j0] = vd.x >> 8; pk[j0] = (vs.x << 8) | (vd.x & 255);
        rk[j0] = atomicAdd(&hist[bk[j0]], 1);
        bk[j1] = vd.z >> 8; pk[j1] = (vs.z << 8) | (vd.z & 255);
        rk[j1] = atomicAdd(&hist[bk[j1]], 1);
      }
    }
  } else {
    const int* p = (const int*)ei;
    #pragma unroll
    for (int k = 0; k < 4; ++k){
      int e = base + (k * 256 + t) * 4;
      if (e < N_EDGES){
        int4 vs = *(const int4*)(p + e);
        int4 vd = *(const int4*)(p + N_EDGES + e);
        int ss[4] = {vs.x, vs.y, vs.z, vs.w};
        int dd[4] = {vd.x, vd.y, vd.z, vd.w};
        #pragma unroll
        for (int j = 0; j < 4; ++j){
          int slot = k * 4 + j;
          bk[slot] = dd[j] >> 8;
          pk[slot] = (ss[j] << 8) | (dd[j] & 255);
          rk[slot] = atomicAdd(&hist[bk[slot]], 1);
        }
      }
    }
  }
  __syncthreads();
  for (int i = t; i < NBUCK; i += 256){
    int h = hist[i];
    baseoff[i] = h ? atomicAdd(&gcursor[i], h) : 0;
  }
  __syncthreads();
  #pragma unroll
  for (int j = 0; j < 16; ++j){
    if (bk[j] >= 0)
      buck[bk[j] * BCAP + baseoff[bk[j]] + rk[j]] = pk[j];
  }
}

// ---------------- CSR finalize (internal bucket-base scan) ----------------
__global__ __launch_bounds__(256) void csr_kernel(const int* __restrict__ gcursor,
                                                  const int* __restrict__ buck,
                                                  unsigned short* __restrict__ csr16,
                                                  int* __restrict__ rowptr){
  __shared__ int sb[256];
  __shared__ int h[256];
  __shared__ int s[256];
  __shared__ int cur[256];
  const int b = blockIdx.x, t = threadIdx.x;
  sb[t] = (t < NBUCK) ? gcursor[t] : 0;
  __syncthreads();
  #pragma unroll
  for (int off = 1; off < 256; off <<= 1){
    int u = (t >= off) ? sb[t - off] : 0;
    __syncthreads();
    sb[t] += u;
    __syncthreads();
  }
  const int gbase = (b == 0) ? 0 : sb[b - 1];
  const int cntb  = gcursor[b];
  h[t] = 0;
  __syncthreads();
  for (int i = t; i < cntb; i += 256)
    atomicAdd(&h[buck[b * BCAP + i] & 255], 1);
  __syncthreads();
  s[t] = h[t];
  __syncthreads();
  #pragma unroll
  for (int off = 1; off < 256; off <<= 1){
    int u = (t >= off) ? s[t - off] : 0;
    __syncthreads();
    s[t] += u;
    __syncthreads();
  }
  int excl = s[t] - h[t];
  int node = b * 256 + t;
  if (node < N_NODES) rowptr[node] = gbase + excl;
  if (b == 0 && t == 0) rowptr[N_NODES] = N_EDGES;
  cur[t] = gbase + excl;
  __syncthreads();
  for (int i = t; i < cntb; i += 256){
    int pkv = buck[b * BCAP + i];
    int pos = atomicAdd(&cur[pkv & 255], 1);
    csr16[pos] = (unsigned short)(((unsigned)pkv) >> 8);
  }
}

// ---------------- fused agg + MFMA GEMM ----------------
// block = 64 nodes. A-tile k<128 = mean (aggregated in-kernel), k>=128 = self row.
// mode 1: relu+dropout, bf16 -> hbf (stride 128); mode 0: fp32 -> out (stride 128)
__global__ __launch_bounds__(256) void fused_kernel(
    const unsigned short* __restrict__ Xsrc,   // bf16 [N][128]
    const int* __restrict__ rowptr, const unsigned short* __restrict__ csr16,
    const unsigned short* __restrict__ Wcat, const float* __restrict__ bias,
    void* __restrict__ outp, int mode)
{
  __shared__ __align__(16) char smem[64 * 132 * 4];   // frag area 32 KB / epilogue 33 KB
  const int t   = threadIdx.x;
  const int w   = t >> 6;
  const int tl  = t & 63;
  const int m15 = tl & 15;
  const int q   = tl >> 4;
  const int row0 = blockIdx.x * 64;

  // B-frag preload (issue early, consumed after barrier)
  bf16x8 bfr[2][8];
  #pragma unroll
  for (int ct = 0; ct < 2; ++ct){
    int col = w * 32 + ct * 16 + m15;
    #pragma unroll
    for (int kc = 0; kc < 8; ++kc)
      bfr[ct][kc] = *(const bf16x8*)(Wcat + (size_t)col * 256 + kc * 32 + q * 8);
  }

  // self-part staging: 64 rows x 128 bf16 -> frag slots kc in [4,8)
  #pragma unroll
  for (int u = 0; u < 4; ++u){
    int g   = t + 256 * u;            // 0..1023
    int row = g >> 4, c = g & 15;     // c = 16B chunk (8 feats)
    int gr = row0 + row; if (gr > N_NODES - 1) gr = N_NODES - 1;
    int4 v = *(const int4*)(Xsrc + (size_t)gr * 128 + c * 8);
    int kc = 4 + (c >> 2), qq = c & 3;
    int f  = (row >> 4) * 8 + kc;
    int slot = (row & 15) + 16 * qq;
    *(int4*)(smem + (size_t)(f * 64 + (slot ^ kc)) * 16) = v;
  }

  // aggregation: 16-lane group q handles 4 nodes; lane m15 covers feats [m15*8, m15*8+8)
  #pragma unroll
  for (int i = 0; i < 4; ++i){
    int row  = w * 16 + q * 4 + i;
    int node = row0 + row;
    float s0=0.f,s1=0.f,s2=0.f,s3=0.f,s4=0.f,s5=0.f,s6=0.f,s7=0.f;
    float inv = 0.f;
    if (node < N_NODES){
      int e0 = rowptr[node], e1 = rowptr[node + 1];
      int e = e0;
      for (; e + 2 <= e1; e += 2){
        int ia = csr16[e], ib = csr16[e + 1];
        int4 va = *(const int4*)(Xsrc + (size_t)ia * 128 + m15 * 8);
        int4 vb = *(const int4*)(Xsrc + (size_t)ib * 128 + m15 * 8);
        acc2(s0, s1, (unsigned)va.x); acc2(s2, s3, (unsigned)va.y);
        acc2(s4, s5, (unsigned)va.z); acc2(s6, s7, (unsigned)va.w);
        acc2(s0, s1, (unsigned)vb.x); acc2(s2, s3, (unsigned)vb.y);
        acc2(s4, s5, (unsigned)vb.z); acc2(s6, s7, (unsigned)vb.w);
      }
      if (e < e1){
        int ia = csr16[e];
        int4 va = *(const int4*)(Xsrc + (size_t)ia * 128 + m15 * 8);
        acc2(s0, s1, (unsigned)va.x); acc2(s2, s3, (unsigned)va.y);
        acc2(s4, s5, (unsigned)va.z); acc2(s6, s7, (unsigned)va.w);
      }
      inv = 1.0f / fmaxf((float)(e1 - e0), 1.0f);
    }
    unsigned short ob[8] = { f2bf(s0*inv), f2bf(s1*inv), f2bf(s2*inv), f2bf(s3*inv),
                             f2bf(s4*inv), f2bf(s5*inv), f2bf(s6*inv), f2bf(s7*inv) };
    int4 o;
    o.x = (unsigned)ob[0] | ((unsigned)ob[1] << 16);
    o.y = (unsigned)ob[2] | ((unsigned)ob[3] << 16);
    o.z = (unsigned)ob[4] | ((unsigned)ob[5] << 16);
    o.w = (unsigned)ob[6] | ((unsigned)ob[7] << 16);
    int kc = m15 >> 2, qq = m15 & 3;          // mean chunk ch = m15 (k < 128)
    int f  = (row >> 4) * 8 + kc;
    int slot = (row & 15) + 16 * qq;
    *(int4*)(smem + (size_t)(f * 64 + (slot ^ kc)) * 16) = o;
  }
  __syncthreads();

  f32x4 acc[4][2];
  #pragma unroll
  for (int rt = 0; rt < 4; ++rt)
    #pragma unroll
    for (int ct = 0; ct < 2; ++ct)
      acc[rt][ct] = (f32x4){0.f, 0.f, 0.f, 0.f};

  #pragma unroll
  for (int kc = 0; kc < 8; ++kc){
    bf16x8 a[4];
    #pragma unroll
    for (int rt = 0; rt < 4; ++rt)
      a[rt] = *(const bf16x8*)(smem + (size_t)((rt * 8 + kc) * 64 + (tl ^ kc)) * 16);
    #pragma unroll
    for (int rt = 0; rt < 4; ++rt)
      #pragma unroll
      for (int ct = 0; ct < 2; ++ct)
        acc[rt][ct] = __builtin_amdgcn_mfma_f32_16x16x32_bf16(a[rt], bfr[ct][kc], acc[rt][ct], 0, 0, 0);
  }
  __syncthreads();

  float* sf = (float*)smem;
  #pragma unroll
  for (int rt = 0; rt < 4; ++rt)
    #pragma unroll
    for (int ct = 0; ct < 2; ++ct)
      #pragma unroll
      for (int i = 0; i < 4; ++i){
        int row = rt * 16 + q * 4 + i;
        int col = w * 32 + ct * 16 + m15;
        sf[row * 132 + col] = acc[rt][ct][i];
      }
  __syncthreads();

  if (mode == 1){
    unsigned short* hout = (unsigned short*)outp;   // hbf, stride 128
    #pragma unroll
    for (int v = 0; v < 4; ++v){
      int s = t + 256 * v;
      int row = s >> 4, c8 = (s & 15) * 8;
      int gr = row0 + row;
      if (gr < N_NODES){
        float4 p0 = *(const float4*)&sf[row * 132 + c8];
        float4 p1 = *(const float4*)&sf[row * 132 + c8 + 4];
        float vals[8] = {p0.x, p0.y, p0.z, p0.w, p1.x, p1.y, p1.z, p1.w};
        unsigned short ob[8];
        #pragma unroll
        for (int j = 0; j < 8; ++j){
          float vv = vals[j] + bias[c8 + j];
          vv = fmaxf(vv, 0.0f);
          vv *= dropout_factor((unsigned)(gr * 128 + c8 + j));
          ob[j] = f2bf(vv);
        }
        int4 o;
        o.x = (unsigned)ob[0] | ((unsigned)ob[1] << 16);
        o.y = (unsigned)ob[2] | ((unsigned)ob[3] << 16);
        o.z = (unsigned)ob[4] | ((unsigned)ob[5] << 16);
        o.w = (unsigned)ob[6] | ((unsigned)ob[7] << 16);
        *(int4*)(hout + (size_t)gr * 128 + c8) = o;
      }
    }
  } else {
    float* of = (float*)outp;
    #pragma unroll
    for (int v = 0; v < 8; ++v){
      int s = t + 256 * v;
      int row = s >> 5, c4 = (s & 31) * 4;
      int gr = row0 + row;
      if (gr < N_NODES){
        float4 p = *(const float4*)&sf[row * 132 + c4];
        p.x += bias[c4 + 0]; p.y += bias[c4 + 1];
        p.z += bias[c4 + 2]; p.w += bias[c4 + 3];
        *(float4*)(of + (size_t)gr * 128 + c4) = p;
      }
    }
  }
}

// ---------------- launch ----------------
extern "C" void kernel_launch(void* const* d_in, const int* in_sizes, int n_in,
                              void* d_out, int out_size, void* d_ws, size_t ws_size,
                              hipStream_t stream)
{
  const float* x   = (const float*)d_in[0];
  const void*  ei  = d_in[1];
  const float* W1l = (const float*)d_in[2];
  const float* W1r = (const float*)d_in[3];
  const float* b1  = (const float*)d_in[4];
  const float* W2l = (const float*)d_in[5];
  const float* W2r = (const float*)d_in[6];
  const float* b2  = (const float*)d_in[7];

  char* ws = (char*)d_ws;
  size_t off = 0;
  unsigned short* Xbf = (unsigned short*)(ws + off); off += (size_t)N_NODES * 128 * 2;  // 12.8 MB
  unsigned short* hbf = (unsigned short*)(ws + off); off += (size_t)N_NODES * 128 * 2;  // 12.8 MB
  int* rowptr      = (int*)(ws + off);  off += (size_t)(N_NODES + 1) * sizeof(int);
  off = (off + 15) & ~(size_t)15;
  unsigned short* csr16 = (unsigned short*)(ws + off); off += (size_t)N_EDGES * 2;
  int* gcursor     = (int*)(ws + off);  off += NBUCK * sizeof(int);
  off = (off + 15) & ~(size_t)15;
  int* buck        = (int*)(ws + off);  off += (size_t)NBUCK * BCAP * sizeof(int);
  unsigned short* Wcat1 = (unsigned short*)(ws + off); off += 128 * 256 * 2;
  unsigned short* Wcat2 = (unsigned short*)(ws + off); off += 128 * 256 * 2;

  hipMemsetAsync(gcursor, 0, NBUCK * sizeof(int), stream);
  prep_bucket_kernel<<<6702, 256, 0, stream>>>(x, W1l, W1r, W2l, W2r, Xbf,
                                               Wcat1, Wcat2, ei, gcursor, buck);
  csr_kernel<<<NBUCK, 256, 0, stream>>>(gcursor, buck, csr16, rowptr);

  fused_kernel<<<(N_NODES + 63) / 64, 256, 0, stream>>>(Xbf, rowptr, csr16,
                                                        Wcat1, b1, (void*)hbf, 1);
  fused_kernel<<<(N_NODES + 63) / 64, 256, 0, stream>>>(hbf, rowptr, csr16,
                                                        Wcat2, b2, d_out, 0);

  (void)in_sizes; (void)n_in; (void)out_size; (void)ws_size;
}

// Round 8
// 218.606 us; speedup vs baseline: 1.3094x; 1.3094x over previous
//
#include <hip/hip_runtime.h>
#include <stdint.h>

#define N_NODES 50000
#define D 128
#define N_EDGES 800000
#define NBUCK 196          // ceil(50000/256) dst buckets (dst>>8)
#define BCAP 8192          // per-bucket capacity (mean 4082)
#define EPB 4096           // edges per block in bucket pass

typedef __attribute__((ext_vector_type(8))) short bf16x8;
typedef __attribute__((ext_vector_type(4))) float f32x4;

// ---------------- bf16 helpers (RNE) ----------------
__device__ __forceinline__ unsigned short f2bf(float f){
  unsigned u = __float_as_uint(f);
  u = u + 0x7FFFu + ((u >> 16) & 1u);
  return (unsigned short)(u >> 16);
}
__device__ __forceinline__ void acc2(float& a, float& b, unsigned w){
  a += __uint_as_float(w << 16);
  b += __uint_as_float(w & 0xFFFF0000u);
}

// ---------------- threefry2x32-20, key=(0,42), partitionable ----------------
__device__ __forceinline__ unsigned rotl32(unsigned x, int r){
  return (x << r) | (x >> (32 - r));
}
__device__ __forceinline__ float dropout_factor(unsigned idx){
  unsigned x0 = 0u, x1 = idx;
  const unsigned ks0 = 0u;
  const unsigned ks1 = 42u;
  const unsigned ks2 = 0x1BD11BDAu ^ 0u ^ 42u;
  x0 += ks0; x1 += ks1;
  #define TFR(r) { x0 += x1; x1 = rotl32(x1,(r)); x1 ^= x0; }
  TFR(13) TFR(15) TFR(26) TFR(6)   x0 += ks1; x1 += ks2 + 1u;
  TFR(17) TFR(29) TFR(16) TFR(24)  x0 += ks2; x1 += ks0 + 2u;
  TFR(13) TFR(15) TFR(26) TFR(6)   x0 += ks0; x1 += ks1 + 3u;
  TFR(17) TFR(29) TFR(16) TFR(24)  x0 += ks1; x1 += ks2 + 4u;
  TFR(13) TFR(15) TFR(26) TFR(6)   x0 += ks2; x1 += ks0 + 5u;
  #undef TFR
  unsigned bits = x0 ^ x1;
  float u = __uint_as_float(0x3F800000u | (bits >> 9)) - 1.0f;
  return (u < 0.8f) ? 1.25f : 0.0f;
}

// ---------------- fused prep + bucket ----------------
// blocks: [0,6250) convert x->A1cat[:,128:256] | [6250,6378) packw1 | [6378,6506) packw2
//         [6506,6702) bucket pass (per-block dtype detect)
__global__ __launch_bounds__(256) void prep_bucket_kernel(
    const float* __restrict__ x,
    const float* __restrict__ W1l, const float* __restrict__ W1r,
    const float* __restrict__ W2l, const float* __restrict__ W2r,
    unsigned short* __restrict__ A1cat,
    unsigned short* __restrict__ Wcat1, unsigned short* __restrict__ Wcat2,
    const void* __restrict__ ei, int* __restrict__ gcursor, int* __restrict__ buck)
{
  int b = blockIdx.x, t = threadIdx.x;
  if (b < 6250){
    int i = b * 256 + t;                 // < 1,600,000 exactly
    int r = i >> 5, c4 = (i & 31) * 4;
    float4 v = *(const float4*)(x + (size_t)r * 128 + c4);
    ushort4 o = make_ushort4(f2bf(v.x), f2bf(v.y), f2bf(v.z), f2bf(v.w));
    *(ushort4*)(A1cat + (size_t)r * 256 + 128 + c4) = o;
    return;
  }
  if (b < 6506){
    int c = (b < 6378) ? (b - 6250) : (b - 6378);
    const float* Wl = (b < 6378) ? W1l : W2l;
    const float* Wr = (b < 6378) ? W1r : W2r;
    unsigned short* Wc = (b < 6378) ? Wcat1 : Wcat2;
    float v = (t < 128) ? Wl[c * 128 + t] : Wr[c * 128 + (t - 128)];
    Wc[c * 256 + t] = f2bf(v);
    return;
  }
  // ---- bucket pass ----
  __shared__ int hist[NBUCK];
  __shared__ int baseoff[NBUCK];
  __shared__ int nz;
  const int bb = b - 6506;
  const int base = bb * EPB;
  if (t == 0) nz = 0;
  for (int i = t; i < NBUCK; i += 256) hist[i] = 0;
  __syncthreads();
  {  // local dtype detect: int64 edges < 2^32 => all high words zero
    const int* p = (const int*)ei;
    int local = 0;
    for (int i = t; i < 1024; i += 256)
      if (p[2 * i + 1] != 0) local = 1;
    if (local) atomicAdd(&nz, 1);
  }
  __syncthreads();
  const int is64 = (nz == 0);

  int pk[16], bk[16], rk[16];
  #pragma unroll
  for (int j = 0; j < 16; ++j) bk[j] = -1;

  if (is64){
    const long long* p = (const long long*)ei;
    #pragma unroll
    for (int k = 0; k < 8; ++k){
      int e = base + (k * 256 + t) * 2;
      if (e < N_EDGES){
        int4 vs = *(const int4*)(p + e);
        int4 vd = *(const int4*)(p + N_EDGES + e);
        int j0 = k * 2, j1 = k * 2 + 1;
        bk[j0] = vd.x >> 8; pk[j0] = (vs.x << 8) | (vd.x & 255);
        rk[j0] = atomicAdd(&hist[bk[j0]], 1);
        bk[j1] = vd.z >> 8; pk[j1] = (vs.z << 8) | (vd.z & 255);
        rk[j1] = atomicAdd(&hist[bk[j1]], 1);
      }
    }
  } else {
    const int* p = (const int*)ei;
    #pragma unroll
    for (int k = 0; k < 4; ++k){
      int e = base + (k * 256 + t) * 4;
      if (e < N_EDGES){
        int4 vs = *(const int4*)(p + e);
        int4 vd = *(const int4*)(p + N_EDGES + e);
        int ss[4] = {vs.x, vs.y, vs.z, vs.w};
        int dd[4] = {vd.x, vd.y, vd.z, vd.w};
        #pragma unroll
        for (int j = 0; j < 4; ++j){
          int slot = k * 4 + j;
          bk[slot] = dd[j] >> 8;
          pk[slot] = (ss[j] << 8) | (dd[j] & 255);
          rk[slot] = atomicAdd(&hist[bk[slot]], 1);
        }
      }
    }
  }
  __syncthreads();
  for (int i = t; i < NBUCK; i += 256){
    int h = hist[i];
    baseoff[i] = h ? atomicAdd(&gcursor[i], h) : 0;
  }
  __syncthreads();
  #pragma unroll
  for (int j = 0; j < 16; ++j){
    if (bk[j] >= 0)
      buck[bk[j] * BCAP + baseoff[bk[j]] + rk[j]] = pk[j];
  }
}

// ---------------- CSR finalize (internal bucket-base scan) ----------------
__global__ __launch_bounds__(256) void csr_kernel(const int* __restrict__ gcursor,
                                                  const int* __restrict__ buck,
                                                  unsigned short* __restrict__ csr16,
                                                  int* __restrict__ rowptr){
  __shared__ int sb[256];
  __shared__ int h[256];
  __shared__ int s[256];
  __shared__ int cur[256];
  const int b = blockIdx.x, t = threadIdx.x;
  sb[t] = (t < NBUCK) ? gcursor[t] : 0;
  __syncthreads();
  #pragma unroll
  for (int off = 1; off < 256; off <<= 1){
    int u = (t >= off) ? sb[t - off] : 0;
    __syncthreads();
    sb[t] += u;
    __syncthreads();
  }
  const int gbase = (b == 0) ? 0 : sb[b - 1];
  const int cntb  = gcursor[b];
  h[t] = 0;
  __syncthreads();
  for (int i = t; i < cntb; i += 256)
    atomicAdd(&h[buck[b * BCAP + i] & 255], 1);
  __syncthreads();
  s[t] = h[t];
  __syncthreads();
  #pragma unroll
  for (int off = 1; off < 256; off <<= 1){
    int u = (t >= off) ? s[t - off] : 0;
    __syncthreads();
    s[t] += u;
    __syncthreads();
  }
  int excl = s[t] - h[t];
  int node = b * 256 + t;
  if (node < N_NODES) rowptr[node] = gbase + excl;
  if (b == 0 && t == 0) rowptr[N_NODES] = N_EDGES;
  cur[t] = gbase + excl;
  __syncthreads();
  for (int i = t; i < cntb; i += 256){
    int pkv = buck[b * BCAP + i];
    int pos = atomicAdd(&cur[pkv & 255], 1);
    csr16[pos] = (unsigned short)(((unsigned)pkv) >> 8);
  }
}

// ---------------- segment mean: wave/node, 4 edge-slots, 4-deep pipeline ----------------
// reads Acat[:,128:256], writes Acat[:,0:128]. Per-lane accumulation order is
// q, 4+q, 8+q, 12+q, ... regardless of loop width -> bitwise stable.
__global__ __launch_bounds__(256) void agg_bf16_kernel(
    unsigned short* __restrict__ Acat, const int* __restrict__ rowptr,
    const unsigned short* __restrict__ csr16)
{
  int node = blockIdx.x * 4 + (threadIdx.x >> 6);
  int lane = threadIdx.x & 63;
  if (node >= N_NODES) return;
  int q  = lane >> 4;
  int fl = lane & 15;
  int e0 = rowptr[node], e1 = rowptr[node + 1];
  float s0=0.f,s1=0.f,s2=0.f,s3=0.f,s4=0.f,s5=0.f,s6=0.f,s7=0.f;

  int e = e0;
  for (; e + 16 <= e1; e += 16){
    int i0 = csr16[e + q];
    int i1 = csr16[e + 4 + q];
    int i2 = csr16[e + 8 + q];
    int i3 = csr16[e + 12 + q];
    int4 v0 = *(const int4*)(Acat + (size_t)i0 * 256 + 128 + fl * 8);
    int4 v1 = *(const int4*)(Acat + (size_t)i1 * 256 + 128 + fl * 8);
    int4 v2 = *(const int4*)(Acat + (size_t)i2 * 256 + 128 + fl * 8);
    int4 v3 = *(const int4*)(Acat + (size_t)i3 * 256 + 128 + fl * 8);
    acc2(s0, s1, (unsigned)v0.x); acc2(s2, s3, (unsigned)v0.y);
    acc2(s4, s5, (unsigned)v0.z); acc2(s6, s7, (unsigned)v0.w);
    acc2(s0, s1, (unsigned)v1.x); acc2(s2, s3, (unsigned)v1.y);
    acc2(s4, s5, (unsigned)v1.z); acc2(s6, s7, (unsigned)v1.w);
    acc2(s0, s1, (unsigned)v2.x); acc2(s2, s3, (unsigned)v2.y);
    acc2(s4, s5, (unsigned)v2.z); acc2(s6, s7, (unsigned)v2.w);
    acc2(s0, s1, (unsigned)v3.x); acc2(s2, s3, (unsigned)v3.y);
    acc2(s4, s5, (unsigned)v3.z); acc2(s6, s7, (unsigned)v3.w);
  }
  for (; e + 8 <= e1; e += 8){
    int i0 = csr16[e + q];
    int i1 = csr16[e + 4 + q];
    int4 v0 = *(const int4*)(Acat + (size_t)i0 * 256 + 128 + fl * 8);
    int4 v1 = *(const int4*)(Acat + (size_t)i1 * 256 + 128 + fl * 8);
    acc2(s0, s1, (unsigned)v0.x); acc2(s2, s3, (unsigned)v0.y);
    acc2(s4, s5, (unsigned)v0.z); acc2(s6, s7, (unsigned)v0.w);
    acc2(s0, s1, (unsigned)v1.x); acc2(s2, s3, (unsigned)v1.y);
    acc2(s4, s5, (unsigned)v1.z); acc2(s6, s7, (unsigned)v1.w);
  }
  for (; e < e1; e += 4){
    int ee = e + q;
    if (ee < e1){
      int i0 = csr16[ee];
      int4 v0 = *(const int4*)(Acat + (size_t)i0 * 256 + 128 + fl * 8);
      acc2(s0, s1, (unsigned)v0.x); acc2(s2, s3, (unsigned)v0.y);
      acc2(s4, s5, (unsigned)v0.z); acc2(s6, s7, (unsigned)v0.w);
    }
  }
  s0 += __shfl_xor(s0, 16); s0 += __shfl_xor(s0, 32);
  s1 += __shfl_xor(s1, 16); s1 += __shfl_xor(s1, 32);
  s2 += __shfl_xor(s2, 16); s2 += __shfl_xor(s2, 32);
  s3 += __shfl_xor(s3, 16); s3 += __shfl_xor(s3, 32);
  s4 += __shfl_xor(s4, 16); s4 += __shfl_xor(s4, 32);
  s5 += __shfl_xor(s5, 16); s5 += __shfl_xor(s5, 32);
  s6 += __shfl_xor(s6, 16); s6 += __shfl_xor(s6, 32);
  s7 += __shfl_xor(s7, 16); s7 += __shfl_xor(s7, 32);
  if (q == 0){
    float inv = 1.0f / fmaxf((float)(e1 - e0), 1.0f);
    unsigned short ob[8] = { f2bf(s0*inv), f2bf(s1*inv), f2bf(s2*inv), f2bf(s3*inv),
                             f2bf(s4*inv), f2bf(s5*inv), f2bf(s6*inv), f2bf(s7*inv) };
    int4 o;
    o.x = (unsigned)ob[0] | ((unsigned)ob[1] << 16);
    o.y = (unsigned)ob[2] | ((unsigned)ob[3] << 16);
    o.z = (unsigned)ob[4] | ((unsigned)ob[5] << 16);
    o.w = (unsigned)ob[6] | ((unsigned)ob[7] << 16);
    *(int4*)(Acat + (size_t)node * 256 + fl * 8) = o;
  }
}

// ---------------- MFMA GEMM: out = Acat @ Wcat^T + b ----------------
__global__ __launch_bounds__(256) void gemm_mfma(
    const unsigned short* __restrict__ Acat, const unsigned short* __restrict__ Wcat,
    const float* __restrict__ bias, void* __restrict__ outp, int mode)
{
  __shared__ __align__(16) char smem[64 * 132 * 4];
  const int t   = threadIdx.x;
  const int w   = t >> 6;
  const int tl  = t & 63;
  const int m15 = tl & 15;
  const int q   = tl >> 4;
  const int row0 = blockIdx.x * 64;

  bf16x8 bfr[2][8];
  #pragma unroll
  for (int ct = 0; ct < 2; ++ct){
    int col = w * 32 + ct * 16 + m15;
    #pragma unroll
    for (int kc = 0; kc < 8; ++kc)
      bfr[ct][kc] = *(const bf16x8*)(Wcat + (size_t)col * 256 + kc * 32 + q * 8);
  }

  #pragma unroll
  for (int u = 0; u < 8; ++u){
    int g   = t + 256 * u;
    int row = g >> 5, ch = g & 31;
    int kc  = ch >> 2, qq = ch & 3;
    int f   = (row >> 4) * 8 + kc;
    int slot = (row & 15) + 16 * qq;
    int gr = row0 + row; if (gr > N_NODES - 1) gr = N_NODES - 1;
    int4 v = *(const int4*)((const char*)Acat + (size_t)gr * 512 + ch * 16);
    *(int4*)(smem + (size_t)(f * 64 + (slot ^ kc)) * 16) = v;
  }
  __syncthreads();

  f32x4 acc[4][2];
  #pragma unroll
  for (int rt = 0; rt < 4; ++rt)
    #pragma unroll
    for (int ct = 0; ct < 2; ++ct)
      acc[rt][ct] = (f32x4){0.f, 0.f, 0.f, 0.f};

  #pragma unroll
  for (int kc = 0; kc < 8; ++kc){
    bf16x8 a[4];
    #pragma unroll
    for (int rt = 0; rt < 4; ++rt)
      a[rt] = *(const bf16x8*)(smem + (size_t)((rt * 8 + kc) * 64 + (tl ^ kc)) * 16);
    #pragma unroll
    for (int rt = 0; rt < 4; ++rt)
      #pragma unroll
      for (int ct = 0; ct < 2; ++ct)
        acc[rt][ct] = __builtin_amdgcn_mfma_f32_16x16x32_bf16(a[rt], bfr[ct][kc], acc[rt][ct], 0, 0, 0);
  }
  __syncthreads();

  float* sf = (float*)smem;
  #pragma unroll
  for (int rt = 0; rt < 4; ++rt)
    #pragma unroll
    for (int ct = 0; ct < 2; ++ct)
      #pragma unroll
      for (int i = 0; i < 4; ++i){
        int row = rt * 16 + q * 4 + i;
        int col = w * 32 + ct * 16 + m15;
        sf[row * 132 + col] = acc[rt][ct][i];
      }
  __syncthreads();

  if (mode == 1){
    unsigned short* hout = (unsigned short*)outp;
    #pragma unroll
    for (int v = 0; v < 4; ++v){
      int s = t + 256 * v;
      int row = s >> 4, c8 = (s & 15) * 8;
      int gr = row0 + row;
      if (gr < N_NODES){
        float4 p0 = *(const float4*)&sf[row * 132 + c8];
        float4 p1 = *(const float4*)&sf[row * 132 + c8 + 4];
        float vals[8] = {p0.x, p0.y, p0.z, p0.w, p1.x, p1.y, p1.z, p1.w};
        unsigned short ob[8];
        #pragma unroll
        for (int j = 0; j < 8; ++j){
          float vv = vals[j] + bias[c8 + j];
          vv = fmaxf(vv, 0.0f);
          vv *= dropout_factor((unsigned)(gr * 128 + c8 + j));
          ob[j] = f2bf(vv);
        }
        int4 o;
        o.x = (unsigned)ob[0] | ((unsigned)ob[1] << 16);
        o.y = (unsigned)ob[2] | ((unsigned)ob[3] << 16);
        o.z = (unsigned)ob[4] | ((unsigned)ob[5] << 16);
        o.w = (unsigned)ob[6] | ((unsigned)ob[7] << 16);
        *(int4*)(hout + (size_t)gr * 256 + 128 + c8) = o;
      }
    }
  } else {
    float* of = (float*)outp;
    #pragma unroll
    for (int v = 0; v < 8; ++v){
      int s = t + 256 * v;
      int row = s >> 5, c4 = (s & 31) * 4;
      int gr = row0 + row;
      if (gr < N_NODES){
        float4 p = *(const float4*)&sf[row * 132 + c4];
        p.x += bias[c4 + 0]; p.y += bias[c4 + 1];
        p.z += bias[c4 + 2]; p.w += bias[c4 + 3];
        *(float4*)(of + (size_t)gr * 128 + c4) = p;
      }
    }
  }
}

// ---------------- launch ----------------
extern "C" void kernel_launch(void* const* d_in, const int* in_sizes, int n_in,
                              void* d_out, int out_size, void* d_ws, size_t ws_size,
                              hipStream_t stream)
{
  const float* x   = (const float*)d_in[0];
  const void*  ei  = d_in[1];
  const float* W1l = (const float*)d_in[2];
  const float* W1r = (const float*)d_in[3];
  const float* b1  = (const float*)d_in[4];
  const float* W2l = (const float*)d_in[5];
  const float* W2r = (const float*)d_in[6];
  const float* b2  = (const float*)d_in[7];

  char* ws = (char*)d_ws;
  unsigned short* A1cat = (unsigned short*)ws;                   // 50000x256 bf16
  size_t off = (size_t)N_NODES * 256 * sizeof(unsigned short);
  int* rowptr      = (int*)(ws + off);  off += (size_t)(N_NODES + 1) * sizeof(int);
  off = (off + 15) & ~(size_t)15;
  unsigned short* csr16 = (unsigned short*)(ws + off); off += (size_t)N_EDGES * sizeof(unsigned short);
  int* gcursor     = (int*)(ws + off);  off += NBUCK * sizeof(int);
  off = (off + 15) & ~(size_t)15;
  int* buck        = (int*)(ws + off);  off += (size_t)NBUCK * BCAP * sizeof(int);
  unsigned short* Wcat1 = (unsigned short*)(ws + off); off += 128 * 256 * sizeof(unsigned short);
  unsigned short* Wcat2 = (unsigned short*)(ws + off); off += 128 * 256 * sizeof(unsigned short);

  unsigned short* A2cat = (unsigned short*)d_out;   // d_out doubles as bf16 [50000][256]

  hipMemsetAsync(gcursor, 0, NBUCK * sizeof(int), stream);
  prep_bucket_kernel<<<6702, 256, 0, stream>>>(x, W1l, W1r, W2l, W2r, A1cat,
                                               Wcat1, Wcat2, ei, gcursor, buck);
  csr_kernel<<<NBUCK, 256, 0, stream>>>(gcursor, buck, csr16, rowptr);

  agg_bf16_kernel<<<(N_NODES + 3) / 4, 256, 0, stream>>>(A1cat, rowptr, csr16);
  gemm_mfma<<<(N_NODES + 63) / 64, 256, 0, stream>>>(A1cat, Wcat1, b1, (void*)A2cat, 1);
  agg_bf16_kernel<<<(N_NODES + 3) / 4, 256, 0, stream>>>(A2cat, rowptr, csr16);
  gemm_mfma<<<(N_NODES + 63) / 64, 256, 0, stream>>>(A2cat, Wcat2, b2, d_out, 0);

  (void)in_sizes; (void)n_in; (void)out_size; (void)ws_size;
}

// Round 9
// 212.296 us; speedup vs baseline: 1.3484x; 1.0297x over previous
//
#include <hip/hip_runtime.h>
#include <stdint.h>

#define N_NODES 50000
#define D 128
#define N_EDGES 800000
#define NBUCK 196          // ceil(50000/256) dst buckets (dst>>8)
#define BCAP 8192          // per-bucket capacity (mean 4082)
#define EPB 4096           // edges per block in bucket pass
#define NDROP 782          // dropout-mask blocks: 782*8192 >= 6.4M elements

typedef __attribute__((ext_vector_type(8))) short bf16x8;
typedef __attribute__((ext_vector_type(4))) float f32x4;

// ---------------- bf16 helpers (RNE) ----------------
__device__ __forceinline__ unsigned short f2bf(float f){
  unsigned u = __float_as_uint(f);
  u = u + 0x7FFFu + ((u >> 16) & 1u);
  return (unsigned short)(u >> 16);
}
__device__ __forceinline__ void acc2(float& a, float& b, unsigned w){
  a += __uint_as_float(w << 16);
  b += __uint_as_float(w & 0xFFFF0000u);
}

// ---------------- threefry2x32-20, key=(0,42), partitionable ----------------
__device__ __forceinline__ unsigned rotl32(unsigned x, int r){
  return (x << r) | (x >> (32 - r));
}
__device__ __forceinline__ int dropout_keep(unsigned idx){
  unsigned x0 = 0u, x1 = idx;
  const unsigned ks0 = 0u;
  const unsigned ks1 = 42u;
  const unsigned ks2 = 0x1BD11BDAu ^ 0u ^ 42u;
  x0 += ks0; x1 += ks1;
  #define TFR(r) { x0 += x1; x1 = rotl32(x1,(r)); x1 ^= x0; }
  TFR(13) TFR(15) TFR(26) TFR(6)   x0 += ks1; x1 += ks2 + 1u;
  TFR(17) TFR(29) TFR(16) TFR(24)  x0 += ks2; x1 += ks0 + 2u;
  TFR(13) TFR(15) TFR(26) TFR(6)   x0 += ks0; x1 += ks1 + 3u;
  TFR(17) TFR(29) TFR(16) TFR(24)  x0 += ks1; x1 += ks2 + 4u;
  TFR(13) TFR(15) TFR(26) TFR(6)   x0 += ks2; x1 += ks0 + 5u;
  #undef TFR
  unsigned bits = x0 ^ x1;
  float u = __uint_as_float(0x3F800000u | (bits >> 9)) - 1.0f;   // [0,1)
  return (u < 0.8f) ? 1 : 0;
}

// ---------------- fused prep + bucket + dropout-mask ----------------
// Stripe-interleave: every 9th block (b%9==8, b/9<NDROP) computes dropout mask
// bits (pure VALU -> co-schedules with the memory-bound sections, m114).
// Remaining linear index L: [0,6250) convert x->A1cat[:,128:256]
//   | [6250,6378) packw1 | [6378,6506) packw2 | [6506,6702) bucket pass
__global__ __launch_bounds__(256) void prep_bucket_kernel(
    const float* __restrict__ x,
    const float* __restrict__ W1l, const float* __restrict__ W1r,
    const float* __restrict__ W2l, const float* __restrict__ W2r,
    unsigned short* __restrict__ A1cat,
    unsigned short* __restrict__ Wcat1, unsigned short* __restrict__ Wcat2,
    const void* __restrict__ ei, int* __restrict__ gcursor, int* __restrict__ buck,
    unsigned* __restrict__ dmask)
{
  int b = blockIdx.x, t = threadIdx.x;
  int g = b / 9, r = b % 9;
  if (r == 8 && g < NDROP){
    // dropout mask: 32 elements/thread -> one uint32
    unsigned base = (unsigned)(g * 8192 + t * 32);
    unsigned w = 0;
    #pragma unroll 2
    for (int j = 0; j < 32; ++j)
      w |= ((unsigned)dropout_keep(base + j)) << j;
    dmask[g * 256 + t] = w;
    return;
  }
  int L = b - ((g < NDROP) ? g : NDROP);

  if (L < 6250){
    int i = L * 256 + t;                 // < 1,600,000 exactly
    int rr = i >> 5, c4 = (i & 31) * 4;
    float4 v = *(const float4*)(x + (size_t)rr * 128 + c4);
    ushort4 o = make_ushort4(f2bf(v.x), f2bf(v.y), f2bf(v.z), f2bf(v.w));
    *(ushort4*)(A1cat + (size_t)rr * 256 + 128 + c4) = o;
    return;
  }
  if (L < 6506){
    int c = (L < 6378) ? (L - 6250) : (L - 6378);
    const float* Wl = (L < 6378) ? W1l : W2l;
    const float* Wr = (L < 6378) ? W1r : W2r;
    unsigned short* Wc = (L < 6378) ? Wcat1 : Wcat2;
    float v = (t < 128) ? Wl[c * 128 + t] : Wr[c * 128 + (t - 128)];
    Wc[c * 256 + t] = f2bf(v);
    return;
  }
  // ---- bucket pass ----
  __shared__ int hist[NBUCK];
  __shared__ int baseoff[NBUCK];
  __shared__ int nz;
  const int bb = L - 6506;
  const int base = bb * EPB;
  if (t == 0) nz = 0;
  for (int i = t; i < NBUCK; i += 256) hist[i] = 0;
  __syncthreads();
  {  // local dtype detect: int64 edges < 2^32 => all high words zero
    const int* p = (const int*)ei;
    int local = 0;
    for (int i = t; i < 1024; i += 256)
      if (p[2 * i + 1] != 0) local = 1;
    if (local) atomicAdd(&nz, 1);
  }
  __syncthreads();
  const int is64 = (nz == 0);

  int pk[16], bk[16], rk[16];
  #pragma unroll
  for (int j = 0; j < 16; ++j) bk[j] = -1;

  if (is64){
    const long long* p = (const long long*)ei;
    #pragma unroll
    for (int k = 0; k < 8; ++k){
      int e = base + (k * 256 + t) * 2;
      if (e < N_EDGES){
        int4 vs = *(const int4*)(p + e);
        int4 vd = *(const int4*)(p + N_EDGES + e);
        int j0 = k * 2, j1 = k * 2 + 1;
        bk[j0] = vd.x >> 8; pk[j0] = (vs.x << 8) | (vd.x & 255);
        rk[j0] = atomicAdd(&hist[bk[j0]], 1);
        bk[j1] = vd.z >> 8; pk[j1] = (vs.z << 8) | (vd.z & 255);
        rk[j1] = atomicAdd(&hist[bk[j1]], 1);
      }
    }
  } else {
    const int* p = (const int*)ei;
    #pragma unroll
    for (int k = 0; k < 4; ++k){
      int e = base + (k * 256 + t) * 4;
      if (e < N_EDGES){
        int4 vs = *(const int4*)(p + e);
        int4 vd = *(const int4*)(p + N_EDGES + e);
        int ss[4] = {vs.x, vs.y, vs.z, vs.w};
        int dd[4] = {vd.x, vd.y, vd.z, vd.w};
        #pragma unroll
        for (int j = 0; j < 4; ++j){
          int slot = k * 4 + j;
          bk[slot] = dd[j] >> 8;
          pk[slot] = (ss[j] << 8) | (dd[j] & 255);
          rk[slot] = atomicAdd(&hist[bk[slot]], 1);
        }
      }
    }
  }
  __syncthreads();
  for (int i = t; i < NBUCK; i += 256){
    int h = hist[i];
    baseoff[i] = h ? atomicAdd(&gcursor[i], h) : 0;
  }
  __syncthreads();
  #pragma unroll
  for (int j = 0; j < 16; ++j){
    if (bk[j] >= 0)
      buck[bk[j] * BCAP + baseoff[bk[j]] + rk[j]] = pk[j];
  }
}

// ---------------- CSR finalize (internal bucket-base scan) ----------------
__global__ __launch_bounds__(256) void csr_kernel(const int* __restrict__ gcursor,
                                                  const int* __restrict__ buck,
                                                  unsigned short* __restrict__ csr16,
                                                  int* __restrict__ rowptr){
  __shared__ int sb[256];
  __shared__ int h[256];
  __shared__ int s[256];
  __shared__ int cur[256];
  const int b = blockIdx.x, t = threadIdx.x;
  sb[t] = (t < NBUCK) ? gcursor[t] : 0;
  __syncthreads();
  #pragma unroll
  for (int off = 1; off < 256; off <<= 1){
    int u = (t >= off) ? sb[t - off] : 0;
    __syncthreads();
    sb[t] += u;
    __syncthreads();
  }
  const int gbase = (b == 0) ? 0 : sb[b - 1];
  const int cntb  = gcursor[b];
  h[t] = 0;
  __syncthreads();
  for (int i = t; i < cntb; i += 256)
    atomicAdd(&h[buck[b * BCAP + i] & 255], 1);
  __syncthreads();
  s[t] = h[t];
  __syncthreads();
  #pragma unroll
  for (int off = 1; off < 256; off <<= 1){
    int u = (t >= off) ? s[t - off] : 0;
    __syncthreads();
    s[t] += u;
    __syncthreads();
  }
  int excl = s[t] - h[t];
  int node = b * 256 + t;
  if (node < N_NODES) rowptr[node] = gbase + excl;
  if (b == 0 && t == 0) rowptr[N_NODES] = N_EDGES;
  cur[t] = gbase + excl;
  __syncthreads();
  for (int i = t; i < cntb; i += 256){
    int pkv = buck[b * BCAP + i];
    int pos = atomicAdd(&cur[pkv & 255], 1);
    csr16[pos] = (unsigned short)(((unsigned)pkv) >> 8);
  }
}

// ---------------- segment mean: wave/node, 4 edge-slots, 4-deep pipeline ----------------
__global__ __launch_bounds__(256) void agg_bf16_kernel(
    unsigned short* __restrict__ Acat, const int* __restrict__ rowptr,
    const unsigned short* __restrict__ csr16)
{
  int node = blockIdx.x * 4 + (threadIdx.x >> 6);
  int lane = threadIdx.x & 63;
  if (node >= N_NODES) return;
  int q  = lane >> 4;
  int fl = lane & 15;
  int e0 = rowptr[node], e1 = rowptr[node + 1];
  float s0=0.f,s1=0.f,s2=0.f,s3=0.f,s4=0.f,s5=0.f,s6=0.f,s7=0.f;

  int e = e0;
  for (; e + 16 <= e1; e += 16){
    int i0 = csr16[e + q];
    int i1 = csr16[e + 4 + q];
    int i2 = csr16[e + 8 + q];
    int i3 = csr16[e + 12 + q];
    int4 v0 = *(const int4*)(Acat + (size_t)i0 * 256 + 128 + fl * 8);
    int4 v1 = *(const int4*)(Acat + (size_t)i1 * 256 + 128 + fl * 8);
    int4 v2 = *(const int4*)(Acat + (size_t)i2 * 256 + 128 + fl * 8);
    int4 v3 = *(const int4*)(Acat + (size_t)i3 * 256 + 128 + fl * 8);
    acc2(s0, s1, (unsigned)v0.x); acc2(s2, s3, (unsigned)v0.y);
    acc2(s4, s5, (unsigned)v0.z); acc2(s6, s7, (unsigned)v0.w);
    acc2(s0, s1, (unsigned)v1.x); acc2(s2, s3, (unsigned)v1.y);
    acc2(s4, s5, (unsigned)v1.z); acc2(s6, s7, (unsigned)v1.w);
    acc2(s0, s1, (unsigned)v2.x); acc2(s2, s3, (unsigned)v2.y);
    acc2(s4, s5, (unsigned)v2.z); acc2(s6, s7, (unsigned)v2.w);
    acc2(s0, s1, (unsigned)v3.x); acc2(s2, s3, (unsigned)v3.y);
    acc2(s4, s5, (unsigned)v3.z); acc2(s6, s7, (unsigned)v3.w);
  }
  for (; e + 8 <= e1; e += 8){
    int i0 = csr16[e + q];
    int i1 = csr16[e + 4 + q];
    int4 v0 = *(const int4*)(Acat + (size_t)i0 * 256 + 128 + fl * 8);
    int4 v1 = *(const int4*)(Acat + (size_t)i1 * 256 + 128 + fl * 8);
    acc2(s0, s1, (unsigned)v0.x); acc2(s2, s3, (unsigned)v0.y);
    acc2(s4, s5, (unsigned)v0.z); acc2(s6, s7, (unsigned)v0.w);
    acc2(s0, s1, (unsigned)v1.x); acc2(s2, s3, (unsigned)v1.y);
    acc2(s4, s5, (unsigned)v1.z); acc2(s6, s7, (unsigned)v1.w);
  }
  for (; e < e1; e += 4){
    int ee = e + q;
    if (ee < e1){
      int i0 = csr16[ee];
      int4 v0 = *(const int4*)(Acat + (size_t)i0 * 256 + 128 + fl * 8);
      acc2(s0, s1, (unsigned)v0.x); acc2(s2, s3, (unsigned)v0.y);
      acc2(s4, s5, (unsigned)v0.z); acc2(s6, s7, (unsigned)v0.w);
    }
  }
  s0 += __shfl_xor(s0, 16); s0 += __shfl_xor(s0, 32);
  s1 += __shfl_xor(s1, 16); s1 += __shfl_xor(s1, 32);
  s2 += __shfl_xor(s2, 16); s2 += __shfl_xor(s2, 32);
  s3 += __shfl_xor(s3, 16); s3 += __shfl_xor(s3, 32);
  s4 += __shfl_xor(s4, 16); s4 += __shfl_xor(s4, 32);
  s5 += __shfl_xor(s5, 16); s5 += __shfl_xor(s5, 32);
  s6 += __shfl_xor(s6, 16); s6 += __shfl_xor(s6, 32);
  s7 += __shfl_xor(s7, 16); s7 += __shfl_xor(s7, 32);
  if (q == 0){
    float inv = 1.0f / fmaxf((float)(e1 - e0), 1.0f);
    unsigned short ob[8] = { f2bf(s0*inv), f2bf(s1*inv), f2bf(s2*inv), f2bf(s3*inv),
                             f2bf(s4*inv), f2bf(s5*inv), f2bf(s6*inv), f2bf(s7*inv) };
    int4 o;
    o.x = (unsigned)ob[0] | ((unsigned)ob[1] << 16);
    o.y = (unsigned)ob[2] | ((unsigned)ob[3] << 16);
    o.z = (unsigned)ob[4] | ((unsigned)ob[5] << 16);
    o.w = (unsigned)ob[6] | ((unsigned)ob[7] << 16);
    *(int4*)(Acat + (size_t)node * 256 + fl * 8) = o;
  }
}

// ---------------- MFMA GEMM: out = Acat @ Wcat^T + b ----------------
__global__ __launch_bounds__(256) void gemm_mfma(
    const unsigned short* __restrict__ Acat, const unsigned short* __restrict__ Wcat,
    const float* __restrict__ bias, const unsigned* __restrict__ dmask,
    void* __restrict__ outp, int mode)
{
  __shared__ __align__(16) char smem[64 * 132 * 4];
  const int t   = threadIdx.x;
  const int w   = t >> 6;
  const int tl  = t & 63;
  const int m15 = tl & 15;
  const int q   = tl >> 4;
  const int row0 = blockIdx.x * 64;

  bf16x8 bfr[2][8];
  #pragma unroll
  for (int ct = 0; ct < 2; ++ct){
    int col = w * 32 + ct * 16 + m15;
    #pragma unroll
    for (int kc = 0; kc < 8; ++kc)
      bfr[ct][kc] = *(const bf16x8*)(Wcat + (size_t)col * 256 + kc * 32 + q * 8);
  }

  #pragma unroll
  for (int u = 0; u < 8; ++u){
    int g   = t + 256 * u;
    int row = g >> 5, ch = g & 31;
    int kc  = ch >> 2, qq = ch & 3;
    int f   = (row >> 4) * 8 + kc;
    int slot = (row & 15) + 16 * qq;
    int gr = row0 + row; if (gr > N_NODES - 1) gr = N_NODES - 1;
    int4 v = *(const int4*)((const char*)Acat + (size_t)gr * 512 + ch * 16);
    *(int4*)(smem + (size_t)(f * 64 + (slot ^ kc)) * 16) = v;
  }
  __syncthreads();

  f32x4 acc[4][2];
  #pragma unroll
  for (int rt = 0; rt < 4; ++rt)
    #pragma unroll
    for (int ct = 0; ct < 2; ++ct)
      acc[rt][ct] = (f32x4){0.f, 0.f, 0.f, 0.f};

  #pragma unroll
  for (int kc = 0; kc < 8; ++kc){
    bf16x8 a[4];
    #pragma unroll
    for (int rt = 0; rt < 4; ++rt)
      a[rt] = *(const bf16x8*)(smem + (size_t)((rt * 8 + kc) * 64 + (tl ^ kc)) * 16);
    #pragma unroll
    for (int rt = 0; rt < 4; ++rt)
      #pragma unroll
      for (int ct = 0; ct < 2; ++ct)
        acc[rt][ct] = __builtin_amdgcn_mfma_f32_16x16x32_bf16(a[rt], bfr[ct][kc], acc[rt][ct], 0, 0, 0);
  }
  __syncthreads();

  float* sf = (float*)smem;
  #pragma unroll
  for (int rt = 0; rt < 4; ++rt)
    #pragma unroll
    for (int ct = 0; ct < 2; ++ct)
      #pragma unroll
      for (int i = 0; i < 4; ++i){
        int row = rt * 16 + q * 4 + i;
        int col = w * 32 + ct * 16 + m15;
        sf[row * 132 + col] = acc[rt][ct][i];
      }
  __syncthreads();

  if (mode == 1){
    unsigned short* hout = (unsigned short*)outp;
    #pragma unroll
    for (int v = 0; v < 4; ++v){
      int s = t + 256 * v;
      int row = s >> 4, c8 = (s & 15) * 8;
      int gr = row0 + row;
      if (gr < N_NODES){
        float4 p0 = *(const float4*)&sf[row * 132 + c8];
        float4 p1 = *(const float4*)&sf[row * 132 + c8 + 4];
        float vals[8] = {p0.x, p0.y, p0.z, p0.w, p1.x, p1.y, p1.z, p1.w};
        unsigned mw = dmask[gr * 4 + (c8 >> 5)];
        unsigned short ob[8];
        #pragma unroll
        for (int j = 0; j < 8; ++j){
          float vv = vals[j] + bias[c8 + j];
          vv = fmaxf(vv, 0.0f);
          float keep = ((mw >> ((c8 & 31) + j)) & 1u) ? 1.25f : 0.0f;
          ob[j] = f2bf(vv * keep);
        }
        int4 o;
        o.x = (unsigned)ob[0] | ((unsigned)ob[1] << 16);
        o.y = (unsigned)ob[2] | ((unsigned)ob[3] << 16);
        o.z = (unsigned)ob[4] | ((unsigned)ob[5] << 16);
        o.w = (unsigned)ob[6] | ((unsigned)ob[7] << 16);
        *(int4*)(hout + (size_t)gr * 256 + 128 + c8) = o;
      }
    }
  } else {
    float* of = (float*)outp;
    #pragma unroll
    for (int v = 0; v < 8; ++v){
      int s = t + 256 * v;
      int row = s >> 5, c4 = (s & 31) * 4;
      int gr = row0 + row;
      if (gr < N_NODES){
        float4 p = *(const float4*)&sf[row * 132 + c4];
        p.x += bias[c4 + 0]; p.y += bias[c4 + 1];
        p.z += bias[c4 + 2]; p.w += bias[c4 + 3];
        *(float4*)(of + (size_t)gr * 128 + c4) = p;
      }
    }
  }
}

// ---------------- launch ----------------
extern "C" void kernel_launch(void* const* d_in, const int* in_sizes, int n_in,
                              void* d_out, int out_size, void* d_ws, size_t ws_size,
                              hipStream_t stream)
{
  const float* x   = (const float*)d_in[0];
  const void*  ei  = d_in[1];
  const float* W1l = (const float*)d_in[2];
  const float* W1r = (const float*)d_in[3];
  const float* b1  = (const float*)d_in[4];
  const float* W2l = (const float*)d_in[5];
  const float* W2r = (const float*)d_in[6];
  const float* b2  = (const float*)d_in[7];

  char* ws = (char*)d_ws;
  unsigned short* A1cat = (unsigned short*)ws;                   // 50000x256 bf16
  size_t off = (size_t)N_NODES * 256 * sizeof(unsigned short);
  int* rowptr      = (int*)(ws + off);  off += (size_t)(N_NODES + 1) * sizeof(int);
  off = (off + 15) & ~(size_t)15;
  unsigned short* csr16 = (unsigned short*)(ws + off); off += (size_t)N_EDGES * sizeof(unsigned short);
  int* gcursor     = (int*)(ws + off);  off += NBUCK * sizeof(int);
  off = (off + 15) & ~(size_t)15;
  int* buck        = (int*)(ws + off);  off += (size_t)NBUCK * BCAP * sizeof(int);
  unsigned short* Wcat1 = (unsigned short*)(ws + off); off += 128 * 256 * sizeof(unsigned short);
  unsigned short* Wcat2 = (unsigned short*)(ws + off); off += 128 * 256 * sizeof(unsigned short);
  unsigned* dmask  = (unsigned*)(ws + off); off += (size_t)NDROP * 256 * sizeof(unsigned);

  unsigned short* A2cat = (unsigned short*)d_out;   // d_out doubles as bf16 [50000][256]

  hipMemsetAsync(gcursor, 0, NBUCK * sizeof(int), stream);
  prep_bucket_kernel<<<6702 + NDROP, 256, 0, stream>>>(x, W1l, W1r, W2l, W2r, A1cat,
                                                       Wcat1, Wcat2, ei, gcursor, buck,
                                                       dmask);
  csr_kernel<<<NBUCK, 256, 0, stream>>>(gcursor, buck, csr16, rowptr);

  agg_bf16_kernel<<<(N_NODES + 3) / 4, 256, 0, stream>>>(A1cat, rowptr, csr16);
  gemm_mfma<<<(N_NODES + 63) / 64, 256, 0, stream>>>(A1cat, Wcat1, b1, dmask, (void*)A2cat, 1);
  agg_bf16_kernel<<<(N_NODES + 3) / 4, 256, 0, stream>>>(A2cat, rowptr, csr16);
  gemm_mfma<<<(N_NODES + 63) / 64, 256, 0, stream>>>(A2cat, Wcat2, b2, dmask, d_out, 0);

  (void)in_sizes; (void)n_in; (void)out_size; (void)ws_size;
}